// Round 1
// baseline (5503.457 us; speedup 1.0000x reference)
//
#include <hip/hip_runtime.h>

#define NBK    64      // NUM_BLOCKS
#define GRID   4096    // NBK*NBK
#define NPTS   512
#define NITER  100
#define WIN    9       // window width: covers all non-underflowed K entries exactly
#define THREADS 512

__device__ __forceinline__ double block_reduce(double v, double* s_red) {
  const int tid = threadIdx.x;
  #pragma unroll
  for (int off = 32; off >= 1; off >>= 1)
    v += __shfl_down(v, off, 64);
  __syncthreads();                 // protect s_red reuse across calls
  if ((tid & 63) == 0) s_red[tid >> 6] = v;
  __syncthreads();
  if (tid == 0) {
    double t = 0.0;
    #pragma unroll
    for (int w = 0; w < THREADS / 64; ++w) t += s_red[w];
    s_red[8] = t;
  }
  __syncthreads();
  return s_red[8];
}

extern "C" __global__ void __launch_bounds__(THREADS)
ot_loss_kernel(const float* __restrict__ pred,
               const float* __restrict__ normed,
               const float* __restrict__ pts,
               float* __restrict__ out)
{
  __shared__ float  s_v[GRID];     // holds KTu, then v (in place)
  __shared__ float  s_nrm[GRID];   // normed, later reused to stash beta
  __shared__ double s_red[9];

  const int b   = blockIdx.x;
  const int tid = threadIdx.x;
  const float* __restrict__ nrm_g  = normed + (size_t)b * GRID;
  const float* __restrict__ pred_g = pred   + (size_t)b * GRID;

  #pragma unroll
  for (int q = 0; q < GRID / THREADS; ++q)
    s_nrm[tid + q * THREADS] = nrm_g[tid + q * THREADS];

  // ---- per-point setup (one point per thread) ----
  const float x = pts[((size_t)b * NPTS + tid) * 2 + 0];
  const float y = pts[((size_t)b * NPTS + tid) * 2 + 1];
  const float x2 = x * x, y2 = y * y;
  const float m2x = -2.0f * x, m2y = -2.0f * y;
  const int jn  = (int)(y * 0.125f);   // home cell (exact: 0.125 = 2^-3)
  const int in0 = (int)(x * 0.125f);

  float ky[WIN], kx[WIN], ydist[WIN], xdist[WIN];
  int rowb[WIN], colc[WIN];
  #pragma unroll
  for (int k = 0; k < WIN; ++k) {
    const int j = jn - 4 + k;
    const float cy = 8.0f * j + 4.0f;
    // replicate reference rounding: (-2y)*c + y*y + c*c
    const float yd = (m2y * cy + y2) + cy * cy;
    ydist[k] = yd;
    ky[k]   = (j >= 0 && j < NBK) ? expf(-yd / 10.0f) : 0.0f;
    rowb[k] = (j < 0 ? 0 : (j > NBK - 1 ? NBK - 1 : j)) * NBK;

    const int i = in0 - 4 + k;
    const float cx = 8.0f * i + 4.0f;
    const float xd = (m2x * cx + x2) + cx * cx;
    xdist[k] = xd;
    kx[k]   = (i >= 0 && i < NBK) ? expf(-xd / 10.0f) : 0.0f;
    colc[k] = (i < 0 ? 0 : (i > NBK - 1 ? NBK - 1 : i));
  }

  float u = 1.0f / NPTS;             // u0; v0 is dead in the reference (KTu first)
  __syncthreads();                   // s_nrm ready

  for (int it = 0; it < NITER; ++it) {
    // zero KTu accumulators
    #pragma unroll
    for (int q = 0; q < GRID / THREADS; ++q)
      s_v[tid + q * THREADS] = 0.0f;
    __syncthreads();

    // KTu[g] += u * Ky * Kx   (scatter; clipped slots have ky/kx == 0 -> add 0)
    #pragma unroll
    for (int k = 0; k < WIN; ++k) {
      const float t = u * ky[k];
      const int base = rowb[k];
      #pragma unroll
      for (int i = 0; i < WIN; ++i)
        atomicAdd(&s_v[base + colc[i]], t * kx[i]);
    }
    __syncthreads();

    // v = normed / (KTu + M_EPS)   (in place)
    #pragma unroll
    for (int q = 0; q < GRID / THREADS; ++q) {
      const int g = tid + q * THREADS;
      s_v[g] = s_nrm[g] / (s_v[g] + 1e-16f);
    }
    __syncthreads();

    // Kv[p] = sum_j Ky_j * sum_i Kx_i * v[j,i]   (gather), u update in-register
    float kv = 0.0f;
    #pragma unroll
    for (int k = 0; k < WIN; ++k) {
      float s = 0.0f;
      const int base = rowb[k];
      #pragma unroll
      for (int i = 0; i < WIN; ++i)
        s = fmaf(kx[i], s_v[base + colc[i]], s);
      kv = fmaf(ky[k], s, kv);
    }
    u = (1.0f / NPTS) / (kv + 1e-16f);
    __syncthreads();                 // protect s_v reads vs next-iter zeroing
  }

  // ---- epilogue: w_dist, ot_obj, loss ----
  // w_dist = sum dist * K * u * v  (per point over its 9x9 window)
  float wd = 0.0f;
  #pragma unroll
  for (int k = 0; k < WIN; ++k) {
    const int base = rowb[k];
    float acc = 0.0f;
    #pragma unroll
    for (int i = 0; i < WIN; ++i) {
      const float Kf   = ky[k] * kx[i];
      const float dist = ydist[k] + xdist[i];
      acc = fmaf(dist * Kf, s_v[base + colc[i]], acc);
    }
    wd += acc;
  }
  double wd_p = (double)wd * (double)u;

  // per-cell pass 1: beta = 10*ln(v); ot_obj, sc, sb partials
  double ot_p = 0.0, sc_p = 0.0, sb_p = 0.0;
  #pragma unroll
  for (int q = 0; q < GRID / THREADS; ++q) {
    const int g = tid + q * THREADS;
    const float beta = 10.0f * logf(s_v[g]);
    const float nm = s_nrm[g];
    const float pr = pred_g[g];
    s_nrm[g] = beta;                 // stash beta for pass 2
    ot_p += (double)nm * (double)beta;
    sc_p += (double)pr;
    sb_p += (double)pr * (double)beta;
  }

  const double wd_tot = block_reduce(wd_p, s_red);
  const double ot_tot = block_reduce(ot_p, s_red);
  const double sc     = block_reduce(sc_p, s_red);
  const double sb     = block_reduce(sb_p, s_red);

  const double denom = sc * sc + 1e-8;
  const double k1 = sc / denom, k2 = sb / denom;

  // pass 2: loss = sum pred * (k1*beta - k2)   (mathematically ~0)
  double loss_p = 0.0;
  #pragma unroll
  for (int q = 0; q < GRID / THREADS; ++q) {
    const int g = tid + q * THREADS;
    loss_p += (double)pred_g[g] * (k1 * (double)s_nrm[g] - k2);
  }
  const double loss_tot = block_reduce(loss_p, s_red);

  if (tid == 0) {
    atomicAdd(out + 0, (float)loss_tot);
    atomicAdd(out + 1, (float)wd_tot);
    atomicAdd(out + 2, (float)ot_tot);
  }
}

extern "C" void kernel_launch(void* const* d_in, const int* in_sizes, int n_in,
                              void* d_out, int out_size, void* d_ws, size_t ws_size,
                              hipStream_t stream) {
  const float* pred   = (const float*)d_in[0];
  const float* normed = (const float*)d_in[1];
  const float* pts    = (const float*)d_in[2];
  float* outp = (float*)d_out;
  const int B = in_sizes[0] / GRID;

  hipMemsetAsync(d_out, 0, (size_t)out_size * sizeof(float), stream);
  ot_loss_kernel<<<B, THREADS, 0, stream>>>(pred, normed, pts, outp);
}

// Round 2
// 3886.701 us; speedup vs baseline: 1.4160x; 1.4160x over previous
//
#include <hip/hip_runtime.h>

#define NBK     64      // NUM_BLOCKS
#define GRID    4096    // NBK*NBK
#define NPTS    512
#define NITER   100
#define WIN     7       // |d|<=3 window; dropped |d|=4 ring has K<=1e-34 (<< M_EPS=1e-16)
#define ROWS_T  4       // rows handled per thread (half 0: rows 0-3, half 1: rows 4-6 + 1 zero pad)
#define THREADS 1024
#define REPS    4       // replicated KTu accumulators to cut atomic contention

__device__ __forceinline__ double block_reduce(double v, double* s_red) {
  const int tid = threadIdx.x;
  #pragma unroll
  for (int off = 32; off >= 1; off >>= 1)
    v += __shfl_down(v, off, 64);
  __syncthreads();                 // protect s_red reuse across calls
  if ((tid & 63) == 0) s_red[tid >> 6] = v;
  __syncthreads();
  if (tid == 0) {
    double t = 0.0;
    #pragma unroll
    for (int w = 0; w < THREADS / 64; ++w) t += s_red[w];
    s_red[16] = t;
  }
  __syncthreads();
  return s_red[16];
}

extern "C" __global__ void __launch_bounds__(THREADS)
ot_loss_kernel(const float* __restrict__ pred,
               const float* __restrict__ normed,
               const float* __restrict__ pts,
               float* __restrict__ out)
{
  __shared__ float  s_ktu[REPS][GRID];  // replicated KTu accumulators
  __shared__ float  s_v2[GRID];         // v (written each iter by divide pass)
  __shared__ float  s_nrm[GRID];        // normed; reused to... stays normed (beta goes to s_v2)
  __shared__ double s_red[17];

  const int b   = blockIdx.x;
  const int tid = threadIdx.x;
  const int p   = tid >> 1;        // point index (2 threads per point)
  const int h   = tid & 1;         // which half of the 7-row window
  const int rep = (tid >> 8) & (REPS - 1);   // 4 waves per replica

  const float* __restrict__ nrm_g  = normed + (size_t)b * GRID;
  const float* __restrict__ pred_g = pred   + (size_t)b * GRID;

  #pragma unroll
  for (int q = 0; q < GRID / THREADS; ++q)
    s_nrm[tid + q * THREADS] = nrm_g[tid + q * THREADS];
  #pragma unroll
  for (int q = 0; q < (REPS * GRID) / THREADS; ++q)
    ((float*)s_ktu)[tid + q * THREADS] = 0.0f;

  // ---- per-point setup (two threads per point) ----
  const float2 pt = ((const float2*)pts)[(size_t)b * NPTS + p];
  const float x = pt.x, y = pt.y;
  const float x2 = x * x, y2 = y * y;
  const float m2x = -2.0f * x, m2y = -2.0f * y;
  const int jn  = (int)(y * 0.125f);   // home cell (exact scale)
  const int in0 = (int)(x * 0.125f);

  // columns: all 7 for both halves
  float kx[WIN]; int colc[WIN];
  #pragma unroll
  for (int i = 0; i < WIN; ++i) {
    const int ii = in0 - 3 + i;
    const float cx = 8.0f * ii + 4.0f;
    const float xd = (m2x * cx + x2) + cx * cx;   // replicate reference rounding
    kx[i]   = (ii >= 0 && ii < NBK) ? expf(-xd / 10.0f) : 0.0f;
    colc[i] = (ii < 0 ? 0 : (ii > NBK - 1 ? NBK - 1 : ii));
  }
  // rows: half 0 -> offsets 0..3, half 1 -> offsets 4..6 (+1 zero-padded row)
  const int r0 = h ? 4 : 0;
  float ky[ROWS_T]; int rowb[ROWS_T];
  #pragma unroll
  for (int k = 0; k < ROWS_T; ++k) {
    const int ko = r0 + k;                 // window row offset 0..7
    const int j  = jn - 3 + ko;
    const float cy = 8.0f * j + 4.0f;
    const float yd = (m2y * cy + y2) + cy * cy;
    const bool ok = (ko < WIN) && (j >= 0) && (j < NBK);
    ky[k]   = ok ? expf(-yd / 10.0f) : 0.0f;
    rowb[k] = (j < 0 ? 0 : (j > NBK - 1 ? NBK - 1 : j)) * NBK;
  }

  float u = 1.0f / NPTS;
  __syncthreads();                   // s_nrm + zeroed s_ktu ready

  for (int it = 0; it < NITER; ++it) {
    // P1: scatter  KTu[g] += u * Ky * Kx  into this wave-group's replica
    #pragma unroll
    for (int k = 0; k < ROWS_T; ++k) {
      const float t = u * ky[k];
      const int base = rowb[k];
      #pragma unroll
      for (int i = 0; i < WIN; ++i)
        atomicAdd(&s_ktu[rep][base + colc[i]], t * kx[i]);
    }
    __syncthreads();

    // P2: v = normed/(sum_reps KTu + M_EPS); re-zero replicas for next iter
    #pragma unroll
    for (int q = 0; q < GRID / THREADS; ++q) {
      const int g = tid + q * THREADS;
      const float sum = (s_ktu[0][g] + s_ktu[1][g]) + (s_ktu[2][g] + s_ktu[3][g]);
      s_v2[g] = s_nrm[g] / (sum + 1e-16f);
      s_ktu[0][g] = 0.0f; s_ktu[1][g] = 0.0f; s_ktu[2][g] = 0.0f; s_ktu[3][g] = 0.0f;
    }
    __syncthreads();

    // P3: gather Kv, update u (no barrier needed: next P1 touches s_ktu only)
    float kv = 0.0f;
    #pragma unroll
    for (int k = 0; k < ROWS_T; ++k) {
      float s = 0.0f;
      const int base = rowb[k];
      #pragma unroll
      for (int i = 0; i < WIN; ++i)
        s = fmaf(kx[i], s_v2[base + colc[i]], s);
      kv = fmaf(ky[k], s, kv);
    }
    kv += __shfl_xor(kv, 1, 64);     // combine the two halves of this point
    u = (1.0f / NPTS) / (kv + 1e-16f);
  }

  // ---- epilogue ----
  // w_dist partial: sum over this half's window of dist * K * v, times u
  float wd = 0.0f;
  #pragma unroll
  for (int k = 0; k < ROWS_T; ++k) {
    const int ko = r0 + k;
    const int j  = jn - 3 + ko;
    const float cy = 8.0f * j + 4.0f;
    const float yd = (m2y * cy + y2) + cy * cy;
    const int base = rowb[k];
    float acc = 0.0f;
    #pragma unroll
    for (int i = 0; i < WIN; ++i) {
      const int ii = in0 - 3 + i;
      const float cx = 8.0f * ii + 4.0f;
      const float xd = (m2x * cx + x2) + cx * cx;
      acc = fmaf((yd + xd) * (ky[k] * kx[i]), s_v2[base + colc[i]], acc);
    }
    wd += acc;
  }
  double wd_p = (double)wd * (double)u;
  const double wd_tot = block_reduce(wd_p, s_red);  // barriers inside protect s_v2

  // per-cell pass: beta = 10*ln(v); stash beta in s_v2; ot/sc/sb partials
  double ot_p = 0.0, sc_p = 0.0, sb_p = 0.0;
  #pragma unroll
  for (int q = 0; q < GRID / THREADS; ++q) {
    const int g = tid + q * THREADS;
    const float beta = 10.0f * logf(s_v2[g]);
    const float nm = s_nrm[g];
    const float pr = pred_g[g];
    s_v2[g] = beta;
    ot_p += (double)nm * (double)beta;
    sc_p += (double)pr;
    sb_p += (double)pr * (double)beta;
  }
  const double ot_tot = block_reduce(ot_p, s_red);
  const double sc     = block_reduce(sc_p, s_red);
  const double sb     = block_reduce(sb_p, s_red);

  const double denom = sc * sc + 1e-8;
  const double k1 = sc / denom, k2 = sb / denom;

  // loss = sum pred * (k1*beta - k2)   (mathematically ~0)
  double loss_p = 0.0;
  #pragma unroll
  for (int q = 0; q < GRID / THREADS; ++q) {
    const int g = tid + q * THREADS;
    loss_p += (double)pred_g[g] * (k1 * (double)s_v2[g] - k2);
  }
  const double loss_tot = block_reduce(loss_p, s_red);

  if (tid == 0) {
    atomicAdd(out + 0, (float)loss_tot);
    atomicAdd(out + 1, (float)wd_tot);
    atomicAdd(out + 2, (float)ot_tot);
  }
}

extern "C" void kernel_launch(void* const* d_in, const int* in_sizes, int n_in,
                              void* d_out, int out_size, void* d_ws, size_t ws_size,
                              hipStream_t stream) {
  const float* pred   = (const float*)d_in[0];
  const float* normed = (const float*)d_in[1];
  const float* pts    = (const float*)d_in[2];
  float* outp = (float*)d_out;
  const int B = in_sizes[0] / GRID;

  hipMemsetAsync(d_out, 0, (size_t)out_size * sizeof(float), stream);
  ot_loss_kernel<<<B, THREADS, 0, stream>>>(pred, normed, pts, outp);
}

// Round 4
// 727.552 us; speedup vs baseline: 7.5643x; 5.3422x over previous
//
#include <hip/hip_runtime.h>

#define NBK     64
#define GRID    4096
#define NPTS    512
#define NITER   100
#define WIN     7       // |d|<=3 window; dropped ring has K<=1e-34 << M_EPS=1e-16
#define ROWS_T  4       // rows per thread (h=0: window rows 0-3, h=1: rows 4-6)
#define THREADS 1024
#define CPT     (GRID/THREADS)   // 4 cells per thread
#define MAXP    (NPTS*WIN*WIN)   // 25088 pair capacity

// pair encoding: f32 K with its 9 low mantissa bits replaced by the point
// index (9 bits exactly for 512 points). K rel-err <= 2^-15, full exponent
// range preserved (the f16 version flushed K<6e-8 to zero and broke ot_obj).
__device__ __forceinline__ unsigned int enc_pair(float K, int p) {
  unsigned int bits = __float_as_uint(K);
  bits = (bits + 0x100u) & 0xFFFFFE00u;   // round mantissa to 14 bits
  return bits | (unsigned int)p;
}
__device__ __forceinline__ float dec_K(unsigned int w) {
  return __uint_as_float(w & 0xFFFFFE00u);
}

// reduce 4 doubles across the block; results left in r[0..3] of every thread
__device__ __forceinline__ void block_reduce4(double* r, double* s_red,
                                              int tid, int lane, int wid) {
  #pragma unroll
  for (int off = 32; off >= 1; off >>= 1) {
    #pragma unroll
    for (int j = 0; j < 4; ++j) r[j] += __shfl_down(r[j], off, 64);
  }
  __syncthreads();
  if (lane == 0) {
    #pragma unroll
    for (int j = 0; j < 4; ++j) s_red[wid * 4 + j] = r[j];
  }
  __syncthreads();
  if (tid == 0) {
    double t0 = 0, t1 = 0, t2 = 0, t3 = 0;
    #pragma unroll
    for (int w = 0; w < THREADS / 64; ++w) {
      t0 += s_red[w * 4 + 0]; t1 += s_red[w * 4 + 1];
      t2 += s_red[w * 4 + 2]; t3 += s_red[w * 4 + 3];
    }
    s_red[64] = t0; s_red[65] = t1; s_red[66] = t2; s_red[67] = t3;
  }
  __syncthreads();
  r[0] = s_red[64]; r[1] = s_red[65]; r[2] = s_red[66]; r[3] = s_red[67];
}

extern "C" __global__ void __launch_bounds__(THREADS)
ot_loss_kernel(const float* __restrict__ pred,
               const float* __restrict__ normed,
               const float* __restrict__ pts,
               float* __restrict__ out)
{
  __shared__ unsigned int   s_pairs[MAXP + 8];   // pair list (idx|K packed)
  __shared__ float          s_v[GRID];           // v each iter (cursors during build)
  __shared__ float          s_nrm[GRID];         // normed (resident)
  __shared__ float          s_u[NPTS];           // u each iter
  __shared__ unsigned short s_off[GRID + 4];     // CSR offsets (exclusive)
  __shared__ unsigned int   s_wpart[16];
  __shared__ double         s_red[68];

  const int b   = blockIdx.x;
  const int tid = threadIdx.x;
  const int p   = tid >> 1;          // point index (2 threads/point)
  const int h   = tid & 1;
  const int lane = tid & 63, wid = tid >> 6;
  const int c0  = tid * CPT;         // this thread's first cell (blocked)
  const int rowj = c0 >> 6;          // all 4 cells share this grid row
  const int coli = c0 & 63;

  const float* __restrict__ nrm_g  = normed + (size_t)b * GRID;
  const float* __restrict__ pred_g = pred   + (size_t)b * GRID;

  unsigned int* hist   = s_pairs;          // [0,4096)   build overlay
  unsigned int* rowsum = s_pairs + GRID;   // [4096,8192) build overlay
  unsigned int* s_cur  = (unsigned int*)s_v;  // cursors overlay v during build

  // ---- setup: load nrm, zero hist ----
  #pragma unroll
  for (int q = 0; q < CPT; ++q) {
    const int g = tid + q * THREADS;
    s_nrm[g] = nrm_g[g];
    hist[g] = 0u;
  }

  // ---- per-point registers (2 threads/point; h splits window rows) ----
  const float2 pt = ((const float2*)pts)[(size_t)b * NPTS + p];
  const float x = pt.x, y = pt.y;
  const float x2 = x * x, y2 = y * y;
  const float m2x = -2.0f * x, m2y = -2.0f * y;
  const int jn  = (int)(y * 0.125f);
  const int in0 = (int)(x * 0.125f);

  float kx[WIN]; int colc[WIN];
  #pragma unroll
  for (int i = 0; i < WIN; ++i) {
    const int ii = in0 - 3 + i;
    const float cx = 8.0f * ii + 4.0f;
    const float xd = (m2x * cx + x2) + cx * cx;   // reference rounding order
    kx[i]   = (ii >= 0 && ii < NBK) ? expf(-xd / 10.0f) : 0.0f;
    colc[i] = (ii < 0 ? 0 : (ii > NBK - 1 ? NBK - 1 : ii));
  }
  const int r0 = h ? 4 : 0;
  float ky[ROWS_T]; int rowb[ROWS_T];
  #pragma unroll
  for (int k = 0; k < ROWS_T; ++k) {
    const int ko = r0 + k;
    const int j  = jn - 3 + ko;
    const float cy = 8.0f * j + 4.0f;
    const float yd = (m2y * cy + y2) + cy * cy;
    const bool ok = (ko < WIN) && (j >= 0) && (j < NBK);
    ky[k]   = ok ? expf(-yd / 10.0f) : 0.0f;
    rowb[k] = (j < 0 ? 0 : (j > NBK - 1 ? NBK - 1 : j)) * NBK;
  }
  __syncthreads();

  // ---- build 1: histogram of home cells; init u ----
  if (h == 0) {
    atomicAdd(&hist[jn * NBK + in0], 1u);
    s_u[p] = 1.0f / NPTS;
  }
  __syncthreads();

  // ---- build 2: vertical 7-box sum ----
  #pragma unroll
  for (int q = 0; q < CPT; ++q) {
    const int i = coli + q;
    unsigned int s = 0;
    #pragma unroll
    for (int dj = -3; dj <= 3; ++dj) {
      const int j = rowj + dj;
      if (j >= 0 && j < NBK) s += hist[j * NBK + i];
    }
    rowsum[rowj * NBK + i] = s;
  }
  __syncthreads();

  // ---- build 3: horizontal 7-box sum -> per-cell counts, then scan ----
  unsigned int cnt[CPT];
  #pragma unroll
  for (int q = 0; q < CPT; ++q) {
    const int i = coli + q;
    unsigned int s = 0;
    #pragma unroll
    for (int di = -3; di <= 3; ++di) {
      const int ii = i + di;
      if (ii >= 0 && ii < NBK) s += rowsum[rowj * NBK + ii];
    }
    cnt[q] = s;
  }
  const unsigned int tsum = cnt[0] + cnt[1] + cnt[2] + cnt[3];
  unsigned int incl = tsum;
  #pragma unroll
  for (int off = 1; off < 64; off <<= 1) {
    const unsigned int n = __shfl_up(incl, off, 64);
    if (lane >= off) incl += n;
  }
  if (lane == 63) s_wpart[wid] = incl;
  __syncthreads();
  if (tid == 0) {
    unsigned int run = 0;
    #pragma unroll
    for (int w = 0; w < THREADS / 64; ++w) {
      const unsigned int t = s_wpart[w];
      s_wpart[w] = run; run += t;
    }
  }
  __syncthreads();
  unsigned int base = s_wpart[wid] + (incl - tsum);
  {
    unsigned int runc = base;
    #pragma unroll
    for (int q = 0; q < CPT; ++q) {
      s_off[c0 + q] = (unsigned short)runc;
      s_cur[c0 + q] = runc;
      runc += cnt[q];
    }
    if (tid == THREADS - 1) s_off[GRID] = (unsigned short)runc;
  }
  __syncthreads();

  // ---- build 4: fill pair lists (one-time atomic cursors) ----
  #pragma unroll
  for (int k = 0; k < ROWS_T; ++k) {
    const int ko = r0 + k;
    const int j  = jn - 3 + ko;
    if (ko < WIN && j >= 0 && j < NBK) {
      #pragma unroll
      for (int i = 0; i < WIN; ++i) {
        const int ii = in0 - 3 + i;
        if (ii >= 0 && ii < NBK) {
          const float K = ky[k] * kx[i];
          const unsigned int pos = atomicAdd(&s_cur[j * NBK + ii], 1u);
          s_pairs[pos] = enc_pair(K, p);
        }
      }
    }
  }
  float u = 1.0f / NPTS;
  __syncthreads();

  // ======== Sinkhorn loop: no atomics, 2 barriers/iter ========
  for (int it = 0; it < NITER; ++it) {
    // P1: per-cell gather  KTu[c] = sum K*u[p] ;  v = nrm/(KTu+eps)
    #pragma unroll
    for (int q = 0; q < CPT; ++q) {
      const int c = c0 + q;
      const int beg = s_off[c], end = s_off[c + 1];
      float acc = 0.0f;
      for (int a0 = beg; a0 < end; a0 += 8) {
        unsigned int w[8]; float uu[8];
        const int endm1 = end - 1;
        #pragma unroll
        for (int e = 0; e < 8; ++e) {
          const int a = a0 + e;
          w[e] = s_pairs[a < endm1 ? a : endm1];   // in-bounds read
          if (a >= end) w[e] = 0u;                 // K=0, idx=0 -> no-op
        }
        #pragma unroll
        for (int e = 0; e < 8; ++e) uu[e] = s_u[w[e] & 0x1FFu];
        #pragma unroll
        for (int e = 0; e < 8; ++e)
          acc = fmaf(dec_K(w[e]), uu[e], acc);
      }
      s_v[c] = s_nrm[c] / (acc + 1e-16f);
    }
    __syncthreads();

    // P2: per-point gather Kv ; u update ; publish u
    float kv = 0.0f;
    #pragma unroll
    for (int k = 0; k < ROWS_T; ++k) {
      float s = 0.0f;
      const int bb = rowb[k];
      #pragma unroll
      for (int i = 0; i < WIN; ++i)
        s = fmaf(kx[i], s_v[bb + colc[i]], s);
      kv = fmaf(ky[k], s, kv);
    }
    kv += __shfl_xor(kv, 1, 64);
    u = (1.0f / NPTS) / (kv + 1e-16f);
    if (h == 0) s_u[p] = u;
    __syncthreads();
  }

  // ======== epilogue ========
  // w_dist partial: sum dist * K * v over this half's window, times u
  float wd = 0.0f;
  #pragma unroll
  for (int k = 0; k < ROWS_T; ++k) {
    const int ko = r0 + k;
    const int j  = jn - 3 + ko;
    const float cy = 8.0f * j + 4.0f;
    const float yd = (m2y * cy + y2) + cy * cy;
    const int bb = rowb[k];
    float acc = 0.0f;
    #pragma unroll
    for (int i = 0; i < WIN; ++i) {
      const int ii = in0 - 3 + i;
      const float cx = 8.0f * ii + 4.0f;
      const float xd = (m2x * cx + x2) + cx * cx;
      acc = fmaf((yd + xd) * (ky[k] * kx[i]), s_v[bb + colc[i]], acc);
    }
    wd += acc;
  }

  // per-cell pass: beta = 10*ln(v); ot/sc/sb partials (read-only on s_v)
  double red[4];
  red[0] = (double)wd * (double)u;   // w_dist partial
  red[1] = 0.0; red[2] = 0.0; red[3] = 0.0;
  #pragma unroll
  for (int q = 0; q < CPT; ++q) {
    const int g = tid + q * THREADS;
    const float beta = 10.0f * logf(s_v[g]);
    const float nm = s_nrm[g];
    const float pr = pred_g[g];
    red[1] += (double)nm * (double)beta;   // ot_obj
    red[2] += (double)pr;                  // sc
    red[3] += (double)pr * (double)beta;   // sb
  }
  block_reduce4(red, s_red, tid, lane, wid);

  if (tid == 0) {
    const double sc = red[2], sb = red[3];
    const double denom = sc * sc + 1e-8;
    const double k1 = sc / denom, k2 = sb / denom;
    const double loss = k1 * sb - k2 * sc;   // == sum pred*(k1*beta-k2), ~0
    atomicAdd(out + 0, (float)loss);
    atomicAdd(out + 1, (float)red[0]);
    atomicAdd(out + 2, (float)red[1]);
  }
}

extern "C" void kernel_launch(void* const* d_in, const int* in_sizes, int n_in,
                              void* d_out, int out_size, void* d_ws, size_t ws_size,
                              hipStream_t stream) {
  const float* pred   = (const float*)d_in[0];
  const float* normed = (const float*)d_in[1];
  const float* pts    = (const float*)d_in[2];
  float* outp = (float*)d_out;
  const int B = in_sizes[0] / GRID;

  hipMemsetAsync(d_out, 0, (size_t)out_size * sizeof(float), stream);
  ot_loss_kernel<<<B, THREADS, 0, stream>>>(pred, normed, pts, outp);
}

// Round 6
// 722.844 us; speedup vs baseline: 7.6136x; 1.0065x over previous
//
#include <hip/hip_runtime.h>

#define NBK     64
#define GRID    4096
#define NPTS    512
#define NITER   100
#define WIN     7       // |d|<=3; dropped |d|=4 ring K<=1e-34 -> safe even vs u~1e13 (WIN=5's 4e-18 was NOT: cost 88 on w_dist)
#define ROWS_T  4       // rows per thread-half (h=0: rows 0-3, h=1: rows 4-6)
#define THREADS 1024
#define CPT     (GRID/THREADS)   // 4 cells per thread
#define MAXP    29192   // 25088 max pairs + <=4096 x2-pad + slack (116.8 KB)

// pair encoding: f32 K with its 9 low mantissa bits replaced by the point
// index. K rel-err <= 2^-15, full exponent range preserved (f16 flushed
// K<6e-8 and broke ot_obj in R2).
__device__ __forceinline__ unsigned int enc_pair(float K, int p) {
  unsigned int bits = __float_as_uint(K);
  bits = (bits + 0x100u) & 0xFFFFFE00u;
  return bits | (unsigned int)p;
}
__device__ __forceinline__ float dec_K(unsigned int w) {
  return __uint_as_float(w & 0xFFFFFE00u);
}

__device__ __forceinline__ void block_reduce4(double* r, double* s_red,
                                              int tid, int lane, int wid) {
  #pragma unroll
  for (int off = 32; off >= 1; off >>= 1) {
    #pragma unroll
    for (int j = 0; j < 4; ++j) r[j] += __shfl_down(r[j], off, 64);
  }
  __syncthreads();
  if (lane == 0) {
    #pragma unroll
    for (int j = 0; j < 4; ++j) s_red[wid * 4 + j] = r[j];
  }
  __syncthreads();
  if (tid == 0) {
    double t0 = 0, t1 = 0, t2 = 0, t3 = 0;
    #pragma unroll
    for (int w = 0; w < THREADS / 64; ++w) {
      t0 += s_red[w * 4 + 0]; t1 += s_red[w * 4 + 1];
      t2 += s_red[w * 4 + 2]; t3 += s_red[w * 4 + 3];
    }
    s_red[64] = t0; s_red[65] = t1; s_red[66] = t2; s_red[67] = t3;
  }
  __syncthreads();
  r[0] = s_red[64]; r[1] = s_red[65]; r[2] = s_red[66]; r[3] = s_red[67];
}

extern "C" __global__ void __launch_bounds__(THREADS)
ot_loss_kernel(const float* __restrict__ pred,
               const float* __restrict__ normed,
               const float* __restrict__ pts,
               float* __restrict__ out)
{
  __shared__ unsigned int s_pairs[MAXP];   // x2-padded CSR pair lists (8B-aligned per cell)
  __shared__ float        s_v[GRID];       // v each iter (cursors overlay during build)
  __shared__ float        s_nrm[GRID];     // normed (resident)
  __shared__ float        s_u[NPTS];       // u each iter
  __shared__ unsigned int s_wpart[16];
  __shared__ double       s_red[68];

  const int b   = blockIdx.x;
  const int tid = threadIdx.x;
  const int p   = tid >> 1;          // point index (2 threads/point)
  const int h   = tid & 1;
  const int lane = tid & 63, wid = tid >> 6;
  const int c0  = tid * CPT;         // this thread's first cell (blocked, 16B-aligned)
  const int rowj = c0 >> 6;
  const int coli = c0 & 63;

  const float* __restrict__ nrm_g  = normed + (size_t)b * GRID;
  const float* __restrict__ pred_g = pred   + (size_t)b * GRID;

  unsigned int* hist   = s_pairs;          // build overlay [0,4096)
  unsigned int* rowsum = s_pairs + GRID;   // build overlay [4096,8192)
  unsigned int* s_cur  = (unsigned int*)s_v;  // cursors overlay v during build

  #pragma unroll
  for (int q = 0; q < CPT; ++q) {
    const int g = tid + q * THREADS;
    s_nrm[g] = nrm_g[g];
    hist[g] = 0u;
  }

  // ---- per-point registers ----
  const float2 pt = ((const float2*)pts)[(size_t)b * NPTS + p];
  const float x = pt.x, y = pt.y;
  const float x2 = x * x, y2 = y * y;
  const float m2x = -2.0f * x, m2y = -2.0f * y;
  const int jn  = (int)(y * 0.125f);   // exact (mult by 2^-3, then trunc)
  const int in0 = (int)(x * 0.125f);

  float kx[WIN]; int colc[WIN];
  #pragma unroll
  for (int i = 0; i < WIN; ++i) {
    const int ii = in0 - 3 + i;
    const float cx = 8.0f * ii + 4.0f;
    const float xd = (m2x * cx + x2) + cx * cx;   // reference rounding order
    kx[i]   = (ii >= 0 && ii < NBK) ? expf(-xd / 10.0f) : 0.0f;
    colc[i] = (ii < 0 ? 0 : (ii > NBK - 1 ? NBK - 1 : ii));
  }
  const int r0 = h ? 4 : 0;
  float ky[ROWS_T]; int rowb[ROWS_T];
  #pragma unroll
  for (int k = 0; k < ROWS_T; ++k) {
    const int ko = r0 + k;
    const int j  = jn - 3 + ko;
    const float cy = 8.0f * j + 4.0f;
    const float yd = (m2y * cy + y2) + cy * cy;
    const bool ok = (ko < WIN) && (j >= 0) && (j < NBK);
    ky[k]   = ok ? expf(-yd / 10.0f) : 0.0f;
    rowb[k] = (j < 0 ? 0 : (j > NBK - 1 ? NBK - 1 : j)) * NBK;
  }
  __syncthreads();

  // ---- build 1: histogram of home cells; init u ----
  if (h == 0) {
    atomicAdd(&hist[jn * NBK + in0], 1u);
    s_u[p] = 1.0f / NPTS;
  }
  __syncthreads();

  // ---- build 2: vertical 7-box sum ----
  #pragma unroll
  for (int q = 0; q < CPT; ++q) {
    const int i = coli + q;
    unsigned int s = 0;
    #pragma unroll
    for (int dj = -3; dj <= 3; ++dj) {
      const int j = rowj + dj;
      if (j >= 0 && j < NBK) s += hist[j * NBK + i];
    }
    rowsum[rowj * NBK + i] = s;
  }
  __syncthreads();

  // ---- build 3: horizontal 7-box sum -> counts, pad to x2, scan ----
  unsigned int pcnt[CPT];
  #pragma unroll
  for (int q = 0; q < CPT; ++q) {
    const int i = coli + q;
    unsigned int s = 0;
    #pragma unroll
    for (int di = -3; di <= 3; ++di) {
      const int ii = i + di;
      if (ii >= 0 && ii < NBK) s += rowsum[rowj * NBK + ii];
    }
    pcnt[q] = (s + 1u) & ~1u;       // 8B-aligned padded length (0 stays 0)
  }
  const unsigned int tsum = pcnt[0] + pcnt[1] + pcnt[2] + pcnt[3];
  unsigned int incl = tsum;
  #pragma unroll
  for (int off = 1; off < 64; off <<= 1) {
    const unsigned int n = __shfl_up(incl, off, 64);
    if (lane >= off) incl += n;
  }
  if (lane == 63) s_wpart[wid] = incl;
  __syncthreads();
  if (tid == 0) {
    unsigned int run = 0;
    #pragma unroll
    for (int w = 0; w < THREADS / 64; ++w) {
      const unsigned int t = s_wpart[w];
      s_wpart[w] = run; run += t;
    }
  }
  __syncthreads();
  // per-cell beg/rounds live in REGISTERS for the whole loop
  unsigned int beg[CPT], rnd[CPT];
  {
    unsigned int runc = s_wpart[wid] + (incl - tsum);
    #pragma unroll
    for (int q = 0; q < CPT; ++q) {
      beg[q] = runc;
      rnd[q] = pcnt[q] >> 1;
      s_cur[c0 + q] = runc;          // fill cursor (overlays s_v)
      runc += pcnt[q];
    }
  }
  __syncthreads();

  // ---- zero the pair array (dummy slots decode to K=0, p=0) ----
  for (int idx = tid; idx < MAXP; idx += THREADS) s_pairs[idx] = 0u;
  __syncthreads();

  // ---- build 4: fill pair lists ----
  #pragma unroll
  for (int k = 0; k < ROWS_T; ++k) {
    const int ko = r0 + k;
    const int j  = jn - 3 + ko;
    if (ko < WIN && j >= 0 && j < NBK) {
      #pragma unroll
      for (int i = 0; i < WIN; ++i) {
        const int ii = in0 - 3 + i;
        if (ii >= 0 && ii < NBK) {
          const float K = ky[k] * kx[i];
          const unsigned int pos = atomicAdd(&s_cur[j * NBK + ii], 1u);
          s_pairs[pos] = enc_pair(K, p);
        }
      }
    }
  }
  float u = 1.0f / NPTS;
  // bitwise period-2 cycle detection (exact early exit)
  float u1 = u;                                  // u_{it-1}
  float u2 = __uint_as_float(0x7FC00000u);       // u_{it-2} sentinel
  int allok_prev = 0;
  __syncthreads();

  // ======== Sinkhorn loop: no atomics, b64 pair reads, 2 barriers/iter ========
  for (int it = 0; it < NITER; ++it) {
    // P1: KTu gather per cell; v = nrm/(KTu+eps)
    float accv[CPT];
    #pragma unroll
    for (int q = 0; q < CPT; ++q) {
      float acc = 0.0f;
      unsigned int addr = beg[q];
      const unsigned int R = rnd[q];
      for (unsigned int r = 0; r < R; ++r) {
        const uint2 w = *reinterpret_cast<const uint2*>(&s_pairs[addr]);
        addr += 2;
        acc = fmaf(dec_K(w.x), s_u[w.x & 511u], acc);
        acc = fmaf(dec_K(w.y), s_u[w.y & 511u], acc);
      }
      accv[q] = acc;
    }
    {
      const float4 nm = *reinterpret_cast<const float4*>(&s_nrm[c0]);
      float4 vv;
      vv.x = nm.x / (accv[0] + 1e-16f);
      vv.y = nm.y / (accv[1] + 1e-16f);
      vv.z = nm.z / (accv[2] + 1e-16f);
      vv.w = nm.w / (accv[3] + 1e-16f);
      *reinterpret_cast<float4*>(&s_v[c0]) = vv;
    }
    __syncthreads();

    // P2: Kv gather per point-half; u update; publish
    float kv = 0.0f;
    #pragma unroll
    for (int k = 0; k < ROWS_T; ++k) {
      float s = 0.0f;
      const int bb = rowb[k];
      #pragma unroll
      for (int i = 0; i < WIN; ++i)
        s = fmaf(kx[i], s_v[bb + colc[i]], s);
      kv = fmaf(ky[k], s, kv);
    }
    kv += __shfl_xor(kv, 1, 64);
    u = (1.0f / NPTS) / (kv + 1e-16f);
    if (h == 0) s_u[p] = u;

    // period-2 check: u_it==u_{it-2} && u_{it-1}==u_{it-3}; exit at it odd
    // reproduces iteration-99 state bit-exactly.
    const int ok = (__float_as_uint(u) == __float_as_uint(u2)) ? 1 : 0;
    u2 = u1; u1 = u;
    const int allok = __syncthreads_and(ok);   // doubles as end-of-iter barrier
    if (allok && allok_prev && (it & 1)) break;
    allok_prev = allok;
  }

  // ======== epilogue ========
  float wd = 0.0f;
  #pragma unroll
  for (int k = 0; k < ROWS_T; ++k) {
    const int ko = r0 + k;
    const int j  = jn - 3 + ko;
    const float cy = 8.0f * j + 4.0f;
    const float yd = (m2y * cy + y2) + cy * cy;
    const int bb = rowb[k];
    float acc = 0.0f;
    #pragma unroll
    for (int i = 0; i < WIN; ++i) {
      const int ii = in0 - 3 + i;
      const float cx = 8.0f * ii + 4.0f;
      const float xd = (m2x * cx + x2) + cx * cx;
      acc = fmaf((yd + xd) * (ky[k] * kx[i]), s_v[bb + colc[i]], acc);
    }
    wd += acc;
  }

  double red[4];
  red[0] = (double)wd * (double)u;
  red[1] = 0.0; red[2] = 0.0; red[3] = 0.0;
  #pragma unroll
  for (int q = 0; q < CPT; ++q) {
    const int g = tid + q * THREADS;
    const float beta = 10.0f * logf(s_v[g]);
    const float nm = s_nrm[g];
    const float pr = pred_g[g];
    red[1] += (double)nm * (double)beta;   // ot_obj
    red[2] += (double)pr;                  // sc
    red[3] += (double)pr * (double)beta;   // sb
  }
  block_reduce4(red, s_red, tid, lane, wid);

  if (tid == 0) {
    const double sc = red[2], sb = red[3];
    const double denom = sc * sc + 1e-8;
    const double k1 = sc / denom, k2 = sb / denom;
    const double loss = k1 * sb - k2 * sc;   // == sum pred*(k1*beta-k2), ~0
    atomicAdd(out + 0, (float)loss);
    atomicAdd(out + 1, (float)red[0]);
    atomicAdd(out + 2, (float)red[1]);
  }
}

extern "C" void kernel_launch(void* const* d_in, const int* in_sizes, int n_in,
                              void* d_out, int out_size, void* d_ws, size_t ws_size,
                              hipStream_t stream) {
  const float* pred   = (const float*)d_in[0];
  const float* normed = (const float*)d_in[1];
  const float* pts    = (const float*)d_in[2];
  float* outp = (float*)d_out;
  const int B = in_sizes[0] / GRID;

  hipMemsetAsync(d_out, 0, (size_t)out_size * sizeof(float), stream);
  ot_loss_kernel<<<B, THREADS, 0, stream>>>(pred, normed, pts, outp);
}

// Round 7
// 667.095 us; speedup vs baseline: 8.2499x; 1.0836x over previous
//
#include <hip/hip_runtime.h>

#define NBK     64
#define GRID    4096
#define NPTS    512
#define NITER   100
#define WIN     7       // |d|<=3; dropped |d|=4 ring K<=1e-34 -> safe even vs u~1e13 (WIN=5 failed w_dist)
#define ROWS_T  4       // rows per thread-half (h=0: rows 0-3, h=1: rows 4-6)
#define THREADS 1024
#define CPT     (GRID/THREADS)   // 4 cells per thread
#define MAXP    29192   // 25088 max pairs + <=4096 x2-pad + slack (116.8 KB)

// pair encoding: f32 K with its 9 low mantissa bits replaced by the point
// index. K rel-err <= 2^-15, full exponent range preserved (f16 flushed
// K<6e-8 and broke ot_obj in R2).
__device__ __forceinline__ unsigned int enc_pair(float K, int p) {
  unsigned int bits = __float_as_uint(K);
  bits = (bits + 0x100u) & 0xFFFFFE00u;
  return bits | (unsigned int)p;
}
__device__ __forceinline__ float dec_K(unsigned int w) {
  return __uint_as_float(w & 0xFFFFFE00u);
}

__device__ __forceinline__ void block_reduce4(double* r, double* s_red,
                                              int tid, int lane, int wid) {
  #pragma unroll
  for (int off = 32; off >= 1; off >>= 1) {
    #pragma unroll
    for (int j = 0; j < 4; ++j) r[j] += __shfl_down(r[j], off, 64);
  }
  __syncthreads();
  if (lane == 0) {
    #pragma unroll
    for (int j = 0; j < 4; ++j) s_red[wid * 4 + j] = r[j];
  }
  __syncthreads();
  if (tid == 0) {
    double t0 = 0, t1 = 0, t2 = 0, t3 = 0;
    #pragma unroll
    for (int w = 0; w < THREADS / 64; ++w) {
      t0 += s_red[w * 4 + 0]; t1 += s_red[w * 4 + 1];
      t2 += s_red[w * 4 + 2]; t3 += s_red[w * 4 + 3];
    }
    s_red[64] = t0; s_red[65] = t1; s_red[66] = t2; s_red[67] = t3;
  }
  __syncthreads();
  r[0] = s_red[64]; r[1] = s_red[65]; r[2] = s_red[66]; r[3] = s_red[67];
}

extern "C" __global__ void __launch_bounds__(THREADS)
ot_loss_kernel(const float* __restrict__ pred,
               const float* __restrict__ normed,
               const float* __restrict__ pts,
               float* __restrict__ out)
{
  __shared__ unsigned int s_pairs[MAXP];   // x2-padded CSR pair lists; build overlays
  __shared__ float        s_v[GRID];       // v each iter (cursors overlay during build)
  __shared__ float        s_nrm[GRID];     // normed (resident)
  __shared__ float        s_u[NPTS];       // u each iter (perm overlay during sort)
  __shared__ unsigned int s_wpart[16];
  __shared__ double       s_red[68];

  const int b   = blockIdx.x;
  const int tid = threadIdx.x;
  const int p   = tid >> 1;          // NEW point index (2 threads/point, post-sort)
  const int h   = tid & 1;
  const int lane = tid & 63, wid = tid >> 6;
  const int c0  = tid * CPT;         // this thread's first cell (blocked)
  const int rowj = c0 >> 6;
  const int coli = c0 & 63;

  const float* __restrict__ nrm_g  = normed + (size_t)b * GRID;
  const float* __restrict__ pred_g = pred   + (size_t)b * GRID;

  unsigned int* hist   = s_pairs;          // build overlay [0,4096): home-cell histogram
  unsigned int* scnd   = s_pairs + GRID;   // build overlay [4096,8192): cellbase / rowsum
  unsigned int* s_cur  = (unsigned int*)s_v;   // CSR cursors overlay v during build
  unsigned int* s_perm = (unsigned int*)s_u;   // perm[new]=old overlays u during sort

  #pragma unroll
  for (int q = 0; q < CPT; ++q) {
    const int g = tid + q * THREADS;
    s_nrm[g] = nrm_g[g];
    hist[g] = 0u;
  }

  // ---- sort 1: histogram of home cells (OLD point order) ----
  const int p_old0 = p;
  const float2 ptO = ((const float2*)pts)[(size_t)b * NPTS + p_old0];
  const int homeO = ((int)(ptO.y * 0.125f)) * NBK + (int)(ptO.x * 0.125f);
  __syncthreads();
  if (h == 0) atomicAdd(&hist[homeO], 1u);
  __syncthreads();

  // ---- sort 2: exclusive scan of home counts -> cellbase (in scnd) ----
  {
    unsigned int hc[CPT];
    #pragma unroll
    for (int q = 0; q < CPT; ++q) hc[q] = hist[c0 + q];
    const unsigned int ts = hc[0] + hc[1] + hc[2] + hc[3];
    unsigned int inc = ts;
    #pragma unroll
    for (int off = 1; off < 64; off <<= 1) {
      const unsigned int n = __shfl_up(inc, off, 64);
      if (lane >= off) inc += n;
    }
    if (lane == 63) s_wpart[wid] = inc;
    __syncthreads();
    if (tid == 0) {
      unsigned int run = 0;
      #pragma unroll
      for (int w = 0; w < THREADS / 64; ++w) {
        const unsigned int t = s_wpart[w];
        s_wpart[w] = run; run += t;
      }
    }
    __syncthreads();
    unsigned int runb = s_wpart[wid] + (inc - ts);
    #pragma unroll
    for (int q = 0; q < CPT; ++q) { scnd[c0 + q] = runb; runb += hc[q]; }
  }
  __syncthreads();

  // ---- sort 3: scatter perm[new]=old via atomic cursors on cellbase ----
  if (h == 0) {
    const unsigned int dst = atomicAdd(&scnd[homeO], 1u);
    s_perm[dst] = (unsigned int)p_old0;
  }
  __syncthreads();

  // ---- re-read own (sorted) point ----
  const unsigned int p_old = s_perm[p];
  const float2 pt = ((const float2*)pts)[(size_t)b * NPTS + p_old];
  __syncthreads();                    // all perm reads done; s_u reusable

  const float x = pt.x, y = pt.y;
  const float x2 = x * x, y2 = y * y;
  const float m2x = -2.0f * x, m2y = -2.0f * y;
  const int jn  = (int)(y * 0.125f);
  const int in0 = (int)(x * 0.125f);

  float kx[WIN]; int colc[WIN];
  #pragma unroll
  for (int i = 0; i < WIN; ++i) {
    const int ii = in0 - 3 + i;
    const float cx = 8.0f * ii + 4.0f;
    const float xd = (m2x * cx + x2) + cx * cx;   // reference rounding order
    kx[i]   = (ii >= 0 && ii < NBK) ? expf(-xd / 10.0f) : 0.0f;
    colc[i] = (ii < 0 ? 0 : (ii > NBK - 1 ? NBK - 1 : ii));
  }
  const int r0 = h ? 4 : 0;
  float ky[ROWS_T]; int rowb[ROWS_T];
  #pragma unroll
  for (int k = 0; k < ROWS_T; ++k) {
    const int ko = r0 + k;
    const int j  = jn - 3 + ko;
    const float cy = 8.0f * j + 4.0f;
    const float yd = (m2y * cy + y2) + cy * cy;
    const bool ok = (ko < WIN) && (j >= 0) && (j < NBK);
    ky[k]   = ok ? expf(-yd / 10.0f) : 0.0f;
    rowb[k] = (j < 0 ? 0 : (j > NBK - 1 ? NBK - 1 : j)) * NBK;
  }

  // ---- build 2: vertical 7-box sum over hist (hist intact) ----
  #pragma unroll
  for (int q = 0; q < CPT; ++q) {
    const int i = coli + q;
    unsigned int s = 0;
    #pragma unroll
    for (int dj = -3; dj <= 3; ++dj) {
      const int j = rowj + dj;
      if (j >= 0 && j < NBK) s += hist[j * NBK + i];
    }
    scnd[rowj * NBK + i] = s;     // overwrites cellbase (done with it)
  }
  __syncthreads();

  // ---- build 3: horizontal 7-box sum -> counts, pad to x2, scan ----
  unsigned int pcnt[CPT];
  #pragma unroll
  for (int q = 0; q < CPT; ++q) {
    const int i = coli + q;
    unsigned int s = 0;
    #pragma unroll
    for (int di = -3; di <= 3; ++di) {
      const int ii = i + di;
      if (ii >= 0 && ii < NBK) s += scnd[rowj * NBK + ii];
    }
    pcnt[q] = (s + 1u) & ~1u;       // 8B-aligned padded length (0 stays 0)
  }
  const unsigned int tsum = pcnt[0] + pcnt[1] + pcnt[2] + pcnt[3];
  unsigned int incl = tsum;
  #pragma unroll
  for (int off = 1; off < 64; off <<= 1) {
    const unsigned int n = __shfl_up(incl, off, 64);
    if (lane >= off) incl += n;
  }
  if (lane == 63) s_wpart[wid] = incl;
  __syncthreads();
  if (tid == 0) {
    unsigned int run = 0;
    #pragma unroll
    for (int w = 0; w < THREADS / 64; ++w) {
      const unsigned int t = s_wpart[w];
      s_wpart[w] = run; run += t;
    }
  }
  __syncthreads();
  unsigned int beg[CPT], rnd[CPT];   // register-resident CSR offsets
  {
    unsigned int runc = s_wpart[wid] + (incl - tsum);
    #pragma unroll
    for (int q = 0; q < CPT; ++q) {
      beg[q] = runc;
      rnd[q] = pcnt[q] >> 1;
      s_cur[c0 + q] = runc;          // fill cursor (overlays s_v)
      runc += pcnt[q];
    }
  }
  if (h == 0) s_u[p] = 1.0f / NPTS;  // s_u free now (perm consumed)
  __syncthreads();

  // ---- zero the pair array (dummy slots decode to K=0, p=0) ----
  for (int idx = tid; idx < MAXP; idx += THREADS) s_pairs[idx] = 0u;
  __syncthreads();

  // ---- build 4: fill pair lists (NEW point indices -> clustered lists) ----
  #pragma unroll
  for (int k = 0; k < ROWS_T; ++k) {
    const int ko = r0 + k;
    const int j  = jn - 3 + ko;
    if (ko < WIN && j >= 0 && j < NBK) {
      #pragma unroll
      for (int i = 0; i < WIN; ++i) {
        const int ii = in0 - 3 + i;
        if (ii >= 0 && ii < NBK) {
          const float K = ky[k] * kx[i];
          const unsigned int pos = atomicAdd(&s_cur[j * NBK + ii], 1u);
          s_pairs[pos] = enc_pair(K, p);
        }
      }
    }
  }
  float u = 1.0f / NPTS;
  // bitwise period-2 cycle detection (exact early exit; free — uses the barrier)
  float u1 = u;
  float u2 = __uint_as_float(0x7FC00000u);
  int allok_prev = 0;
  __syncthreads();

  // ======== Sinkhorn loop: no atomics, b64 pair reads, 2 barriers/iter ========
  for (int it = 0; it < NITER; ++it) {
    // P1: KTu gather per cell; v = nrm/(KTu+eps)
    float accv[CPT];
    #pragma unroll
    for (int q = 0; q < CPT; ++q) {
      float acc = 0.0f;
      unsigned int addr = beg[q];
      const unsigned int R = rnd[q];
      for (unsigned int r = 0; r < R; ++r) {
        const uint2 w = *reinterpret_cast<const uint2*>(&s_pairs[addr]);
        addr += 2;
        acc = fmaf(dec_K(w.x), s_u[w.x & 511u], acc);
        acc = fmaf(dec_K(w.y), s_u[w.y & 511u], acc);
      }
      accv[q] = acc;
    }
    {
      const float4 nm = *reinterpret_cast<const float4*>(&s_nrm[c0]);
      float4 vv;
      vv.x = nm.x / (accv[0] + 1e-16f);
      vv.y = nm.y / (accv[1] + 1e-16f);
      vv.z = nm.z / (accv[2] + 1e-16f);
      vv.w = nm.w / (accv[3] + 1e-16f);
      *reinterpret_cast<float4*>(&s_v[c0]) = vv;
    }
    __syncthreads();

    // P2: Kv gather per point-half; u update; publish
    float kv = 0.0f;
    #pragma unroll
    for (int k = 0; k < ROWS_T; ++k) {
      float s = 0.0f;
      const float* vrow = &s_v[rowb[k]];
      #pragma unroll
      for (int i = 0; i < WIN; ++i)
        s = fmaf(kx[i], vrow[colc[i]], s);
      kv = fmaf(ky[k], s, kv);
    }
    kv += __shfl_xor(kv, 1, 64);
    u = (1.0f / NPTS) / (kv + 1e-16f);
    if (h == 0) s_u[p] = u;

    const int ok = (__float_as_uint(u) == __float_as_uint(u2)) ? 1 : 0;
    u2 = u1; u1 = u;
    const int allok = __syncthreads_and(ok);   // doubles as end-of-iter barrier
    if (allok && allok_prev && (it & 1)) break;
    allok_prev = allok;
  }

  // ======== epilogue ========
  float wd = 0.0f;
  #pragma unroll
  for (int k = 0; k < ROWS_T; ++k) {
    const int ko = r0 + k;
    const int j  = jn - 3 + ko;
    const float cy = 8.0f * j + 4.0f;
    const float yd = (m2y * cy + y2) + cy * cy;
    const float* vrow = &s_v[rowb[k]];
    float acc = 0.0f;
    #pragma unroll
    for (int i = 0; i < WIN; ++i) {
      const int ii = in0 - 3 + i;
      const float cx = 8.0f * ii + 4.0f;
      const float xd = (m2x * cx + x2) + cx * cx;
      acc = fmaf((yd + xd) * (ky[k] * kx[i]), vrow[colc[i]], acc);
    }
    wd += acc;
  }

  double red[4];
  red[0] = (double)wd * (double)u;
  red[1] = 0.0; red[2] = 0.0; red[3] = 0.0;
  #pragma unroll
  for (int q = 0; q < CPT; ++q) {
    const int g = tid + q * THREADS;
    const float beta = 10.0f * logf(s_v[g]);
    const float nm = s_nrm[g];
    const float pr = pred_g[g];
    red[1] += (double)nm * (double)beta;   // ot_obj
    red[2] += (double)pr;                  // sc
    red[3] += (double)pr * (double)beta;   // sb
  }
  block_reduce4(red, s_red, tid, lane, wid);

  if (tid == 0) {
    const double sc = red[2], sb = red[3];
    const double denom = sc * sc + 1e-8;
    const double k1 = sc / denom, k2 = sb / denom;
    const double loss = k1 * sb - k2 * sc;   // == sum pred*(k1*beta-k2), ~0
    atomicAdd(out + 0, (float)loss);
    atomicAdd(out + 1, (float)red[0]);
    atomicAdd(out + 2, (float)red[1]);
  }
}

extern "C" void kernel_launch(void* const* d_in, const int* in_sizes, int n_in,
                              void* d_out, int out_size, void* d_ws, size_t ws_size,
                              hipStream_t stream) {
  const float* pred   = (const float*)d_in[0];
  const float* normed = (const float*)d_in[1];
  const float* pts    = (const float*)d_in[2];
  float* outp = (float*)d_out;
  const int B = in_sizes[0] / GRID;

  hipMemsetAsync(d_out, 0, (size_t)out_size * sizeof(float), stream);
  ot_loss_kernel<<<B, THREADS, 0, stream>>>(pred, normed, pts, outp);
}